// Round 6
// baseline (406.191 us; speedup 1.0000x reference)
//
#include <hip/hip_runtime.h>
#include <cstdint>
#include <cstddef>

typedef unsigned short u16;
typedef __attribute__((ext_vector_type(8))) short bf16x8;   // 8 bf16 = 4 VGPRs
typedef __attribute__((ext_vector_type(4))) float f32x4;    // MFMA 16x16 C/D

// ---------- helpers ----------
__device__ __forceinline__ u16 f2b(float f) {
    union { float f; unsigned u; } un; un.f = f;
    unsigned r = un.u + 0x7fffu + ((un.u >> 16) & 1u);   // RNE
    return (u16)(r >> 16);
}
__device__ __forceinline__ u16 f2b_trunc(float f) {
    union { float f; unsigned u; } un; un.f = f;
    return (u16)(un.u >> 16);
}
__device__ __forceinline__ float fast_exp2(float x) {
#if __has_builtin(__builtin_amdgcn_exp2f)
    return __builtin_amdgcn_exp2f(x);
#else
    return exp2f(x);
#endif
}

// async global->LDS DMA, 16B per lane (wave-uniform base + lane*16 semantics).
__device__ __forceinline__ void stage16(const u16* g, u16* l) {
    __builtin_amdgcn_global_load_lds(
        (const __attribute__((address_space(1))) void*)g,
        (__attribute__((address_space(3))) void*)l, 16, 0, 0);
}

// ---------- cast fp32 -> bf16, 4 elems/thread ----------
__global__ __launch_bounds__(256) void cast_bf16_x4(const float* __restrict__ in,
                                                    u16* __restrict__ out, int n4) {
    int i = blockIdx.x * 256 + threadIdx.x;
    if (i >= n4) return;
    float4 v = ((const float4*)in)[i];
    ushort4 o;
    o.x = f2b(v.x); o.y = f2b(v.y); o.z = f2b(v.z); o.w = f2b(v.w);
    ((ushort4*)out)[i] = o;
}

// ---------- transpose + cast: w[K][N] f32 -> wT[N][K] bf16 ----------
__global__ __launch_bounds__(256) void transpose_cast(const float* __restrict__ in,
                                                      u16* __restrict__ out, int K, int N) {
    __shared__ float t[32][33];
    const int n0 = blockIdx.x * 32, k0 = blockIdx.y * 32;
    const int tx = threadIdx.x, ty = threadIdx.y;           // 32 x 8
#pragma unroll
    for (int i = 0; i < 4; ++i)
        t[ty + i * 8][tx] = in[(size_t)(k0 + ty + i * 8) * N + n0 + tx];
    __syncthreads();
#pragma unroll
    for (int i = 0; i < 4; ++i)
        out[(size_t)(n0 + ty + i * 8) * K + k0 + tx] = f2b(t[tx][ty + i * 8]);
}

// ---------- GEMM 128x128: C[M,N] = A[M,K] @ BT[N,K]^T  (+bias, epilogue) ----------
// LDS: unpadded [row][64] XOR-swizzled 16B groups; staged by global_load_lds.
// EPI 0: bf16 out = acc + bias
// EPI 2: bf16 out = gelu_exact(acc + bias)
// EPI 3: qkv: cols<1536 -> bf16 out (q,k); cols>=1536 -> vt transposed
template <int EPI>
__global__ __launch_bounds__(256, 3)
void gemm_bf16(const u16* __restrict__ A, const u16* __restrict__ BT,
               const float* __restrict__ bias,
               void* __restrict__ outp, u16* __restrict__ vt, int M, int N, int K) {
    __shared__ __align__(16) u16 Ash[128 * 64];
    __shared__ __align__(16) u16 Bsh[128 * 64];
    const int m0 = blockIdx.y * 128, n0 = blockIdx.x * 128;
    const int tid = threadIdx.x;
    const int w = tid >> 6, lane = tid & 63;
    const int l16 = lane & 15, quad = lane >> 4;
    const int wm = (w >> 1) * 64, wn = (w & 1) * 64;

    const int srow = lane >> 3;                       // row within 8-row chunk
    const int sgrp = (lane & 7) ^ (srow & 7);         // logical 16B group to fetch
    const int xk = l16 & 7;                           // read-side swizzle key

    const f32x4 vzero = {0.f, 0.f, 0.f, 0.f};
    f32x4 acc[4][4];
#pragma unroll
    for (int i = 0; i < 4; ++i)
#pragma unroll
        for (int j = 0; j < 4; ++j) acc[i][j] = vzero;

    for (int k0 = 0; k0 < K; k0 += 64) {
#pragma unroll
        for (int it = 0; it < 4; ++it) {
            const int c = it * 4 + w;
            const int r = c * 8 + srow;
            stage16(A + (size_t)(m0 + r) * K + k0 + sgrp * 8, &Ash[c * 512 + lane * 8]);
        }
#pragma unroll
        for (int it = 0; it < 4; ++it) {
            const int c = it * 4 + w;
            const int r = c * 8 + srow;
            stage16(BT + (size_t)(n0 + r) * K + k0 + sgrp * 8, &Bsh[c * 512 + lane * 8]);
        }
        __syncthreads();

        bf16x8 af[4][2], bfr[4][2];
#pragma unroll
        for (int mt = 0; mt < 4; ++mt)
#pragma unroll
            for (int s = 0; s < 2; ++s)
                af[mt][s] = *(const bf16x8*)&Ash[(wm + mt * 16 + l16) * 64 +
                                                 (((s << 2) + quad) ^ xk) * 8];
#pragma unroll
        for (int nt = 0; nt < 4; ++nt)
#pragma unroll
            for (int s = 0; s < 2; ++s)
                bfr[nt][s] = *(const bf16x8*)&Bsh[(wn + nt * 16 + l16) * 64 +
                                                  (((s << 2) + quad) ^ xk) * 8];
#pragma unroll
        for (int mt = 0; mt < 4; ++mt)
#pragma unroll
            for (int nt = 0; nt < 4; ++nt)
#pragma unroll
                for (int s = 0; s < 2; ++s)
                    acc[mt][nt] = __builtin_amdgcn_mfma_f32_16x16x32_bf16(
                        af[mt][s], bfr[nt][s], acc[mt][nt], 0, 0, 0);
        __syncthreads();
    }

    if (EPI == 3 && n0 >= 1536) {
#pragma unroll
        for (int mt = 0; mt < 4; ++mt) {
#pragma unroll
            for (int nt = 0; nt < 4; ++nt) {
                const int col = n0 + wn + nt * 16 + l16;
                const int c = col - 1536;
                const int h = c >> 6, d = c & 63;
                const float bv = bias[col];
                const int row0 = m0 + wm + mt * 16 + quad * 4;
                const int b = row0 >> 11, tok = row0 & 2047;
                ushort4 o;
                o.x = f2b(acc[mt][nt][0] + bv);
                o.y = f2b(acc[mt][nt][1] + bv);
                o.z = f2b(acc[mt][nt][2] + bv);
                o.w = f2b(acc[mt][nt][3] + bv);
                *(ushort4*)&vt[(size_t)(((b * 12 + h) << 6) + d) * 2048 + tok] = o;
            }
        }
        return;
    }

#pragma unroll
    for (int mt = 0; mt < 4; ++mt) {
#pragma unroll
        for (int nt = 0; nt < 4; ++nt) {
            const int col = n0 + wn + nt * 16 + l16;
            const float bv = bias[col];
#pragma unroll
            for (int r = 0; r < 4; ++r) {
                const int row = m0 + wm + mt * 16 + quad * 4 + r;
                float v = acc[mt][nt][r] + bv;
                if (EPI == 2) {
                    v = 0.5f * v * (1.f + erff(v * 0.70710678118654752f));
                    ((u16*)outp)[(size_t)row * N + col] = f2b(v);
                } else {
                    ((u16*)outp)[(size_t)row * N + col] = f2b(v);
                }
            }
        }
    }
}

// ---------- GEMM 64x128 (residual f32 out) for N=768 cases ----------
__global__ __launch_bounds__(256, 4)
void gemm_bf16_r64(const u16* __restrict__ A, const u16* __restrict__ BT,
                   const float* __restrict__ bias, const float* __restrict__ resid,
                   float* __restrict__ outp, int M, int N, int K) {
    __shared__ __align__(16) u16 Ash[64 * 64];
    __shared__ __align__(16) u16 Bsh[128 * 64];
    const int m0 = blockIdx.y * 64, n0 = blockIdx.x * 128;
    const int tid = threadIdx.x;
    const int w = tid >> 6, lane = tid & 63;
    const int l16 = lane & 15, quad = lane >> 4;
    const int wm = (w >> 1) * 32, wn = (w & 1) * 64;

    const int srow = lane >> 3;
    const int sgrp = (lane & 7) ^ (srow & 7);
    const int xk = l16 & 7;

    const f32x4 vzero = {0.f, 0.f, 0.f, 0.f};
    f32x4 acc[2][4];
#pragma unroll
    for (int i = 0; i < 2; ++i)
#pragma unroll
        for (int j = 0; j < 4; ++j) acc[i][j] = vzero;

    for (int k0 = 0; k0 < K; k0 += 64) {
#pragma unroll
        for (int it = 0; it < 2; ++it) {            // A: 8 chunks of 8 rows
            const int c = it * 4 + w;
            const int r = c * 8 + srow;
            stage16(A + (size_t)(m0 + r) * K + k0 + sgrp * 8, &Ash[c * 512 + lane * 8]);
        }
#pragma unroll
        for (int it = 0; it < 4; ++it) {            // B: 16 chunks
            const int c = it * 4 + w;
            const int r = c * 8 + srow;
            stage16(BT + (size_t)(n0 + r) * K + k0 + sgrp * 8, &Bsh[c * 512 + lane * 8]);
        }
        __syncthreads();

        bf16x8 af[2][2], bfr[4][2];
#pragma unroll
        for (int mt = 0; mt < 2; ++mt)
#pragma unroll
            for (int s = 0; s < 2; ++s)
                af[mt][s] = *(const bf16x8*)&Ash[(wm + mt * 16 + l16) * 64 +
                                                 (((s << 2) + quad) ^ xk) * 8];
#pragma unroll
        for (int nt = 0; nt < 4; ++nt)
#pragma unroll
            for (int s = 0; s < 2; ++s)
                bfr[nt][s] = *(const bf16x8*)&Bsh[(wn + nt * 16 + l16) * 64 +
                                                  (((s << 2) + quad) ^ xk) * 8];
#pragma unroll
        for (int mt = 0; mt < 2; ++mt)
#pragma unroll
            for (int nt = 0; nt < 4; ++nt)
#pragma unroll
                for (int s = 0; s < 2; ++s)
                    acc[mt][nt] = __builtin_amdgcn_mfma_f32_16x16x32_bf16(
                        af[mt][s], bfr[nt][s], acc[mt][nt], 0, 0, 0);
        __syncthreads();
    }

#pragma unroll
    for (int mt = 0; mt < 2; ++mt) {
#pragma unroll
        for (int nt = 0; nt < 4; ++nt) {
            const int col = n0 + wn + nt * 16 + l16;
            const float bv = bias[col];
#pragma unroll
            for (int r = 0; r < 4; ++r) {
                const int row = m0 + wm + mt * 16 + quad * 4 + r;
                outp[(size_t)row * N + col] =
                    acc[mt][nt][r] + bv + resid[(size_t)row * N + col];
            }
        }
    }
}

// ---------- fused flash attention, max-free softmax, double-buffered K/V ----------
// One barrier per k-tile: barrier drains the DMA issued one full compute-phase
// ago, then next tile's DMA is issued immediately (overlaps current compute).
__global__ __launch_bounds__(256, 3)
void attn_fused(const u16* __restrict__ qkv, const u16* __restrict__ vt,
                u16* __restrict__ ctx) {
    constexpr int LDP = 68;   // P per wave [q(32)][tok(64)]
    __shared__ __align__(16) u16 Ksh[2][64 * 64];
    __shared__ __align__(16) u16 Vsh[2][64 * 64];
    __shared__ __align__(16) short Psh[4 * 32 * LDP];

    const int q0 = blockIdx.x * 128;
    const int h = blockIdx.y, b = blockIdx.z;
    const int tid = threadIdx.x;
    const int w = tid >> 6, lane = tid & 63, l16 = lane & 15, quad = lane >> 4;
    short* Pw = Psh + w * 32 * LDP;

    const int srow = lane >> 3;
    const int sgrp = (lane & 7) ^ (srow & 7);
    const int xk = l16 & 7;

    const u16* Qp = qkv + (size_t)b * 2048 * 2304 + h * 64;
    const u16* Kp = Qp + 768;
    const u16* Vtp = vt + ((size_t)(b * 12 + h) << 6) * 2048;

    bf16x8 qf[2][2];
#pragma unroll
    for (int mt = 0; mt < 2; ++mt)
#pragma unroll
        for (int s = 0; s < 2; ++s)
            qf[mt][s] = *(const bf16x8*)(Qp +
                (size_t)(q0 + w * 32 + mt * 16 + l16) * 2304 + s * 32 + quad * 8);

    const f32x4 vzero = {0.f, 0.f, 0.f, 0.f};
    f32x4 oacc[2][4];
    float l_r[2][4];
#pragma unroll
    for (int mt = 0; mt < 2; ++mt) {
#pragma unroll
        for (int dt = 0; dt < 4; ++dt) oacc[mt][dt] = vzero;
#pragma unroll
        for (int r = 0; r < 4; ++r) l_r[mt][r] = 0.f;
    }

    constexpr float SCALE = 0.18033688011112042f;   // log2(e)/8

    // prologue: stage tile 0 into buffer 0
#pragma unroll
    for (int it = 0; it < 2; ++it) {
        const int c = it * 4 + w;
        const int r = c * 8 + srow;
        stage16(Kp + (size_t)r * 2304 + sgrp * 8, &Ksh[0][c * 512 + lane * 8]);
        stage16(Vtp + (size_t)r * 2048 + sgrp * 8, &Vsh[0][c * 512 + lane * 8]);
    }

    int cur = 0;
    for (int kt = 0; kt < 2048; kt += 64) {
        __syncthreads();   // drains this wave's DMA for buf[cur]; fences buf[cur^1] readers

        if (kt + 64 < 2048) {
            const int nxt = cur ^ 1;
#pragma unroll
            for (int it = 0; it < 2; ++it) {
                const int c = it * 4 + w;
                const int r = c * 8 + srow;
                stage16(Kp + (size_t)(kt + 64 + r) * 2304 + sgrp * 8,
                        &Ksh[nxt][c * 512 + lane * 8]);
                stage16(Vtp + (size_t)r * 2048 + (kt + 64) + sgrp * 8,
                        &Vsh[nxt][c * 512 + lane * 8]);
            }
        }

        const u16* Kc = Ksh[cur];
        const u16* Vc = Vsh[cur];

        bf16x8 kfr[4][2];
#pragma unroll
        for (int nt = 0; nt < 4; ++nt)
#pragma unroll
            for (int s = 0; s < 2; ++s)
                kfr[nt][s] = *(const bf16x8*)&Kc[(nt * 16 + l16) * 64 +
                                                 (((s << 2) + quad) ^ xk) * 8];

        f32x4 sacc[2][4];
#pragma unroll
        for (int mt = 0; mt < 2; ++mt)
#pragma unroll
            for (int nt = 0; nt < 4; ++nt) {
                sacc[mt][nt] = vzero;
#pragma unroll
                for (int s = 0; s < 2; ++s)
                    sacc[mt][nt] = __builtin_amdgcn_mfma_f32_16x16x32_bf16(
                        qf[mt][s], kfr[nt][s], sacc[mt][nt], 0, 0, 0);
            }

#pragma unroll
        for (int mt = 0; mt < 2; ++mt) {
#pragma unroll
            for (int r = 0; r < 4; ++r) {
                float p0 = fast_exp2(sacc[mt][0][r] * SCALE);
                float p1 = fast_exp2(sacc[mt][1][r] * SCALE);
                float p2 = fast_exp2(sacc[mt][2][r] * SCALE);
                float p3 = fast_exp2(sacc[mt][3][r] * SCALE);
                l_r[mt][r] += (p0 + p1) + (p2 + p3);
                short* prow = &Pw[(mt * 16 + quad * 4 + r) * LDP + l16];
                prow[0]  = (short)f2b_trunc(p0);
                prow[16] = (short)f2b_trunc(p1);
                prow[32] = (short)f2b_trunc(p2);
                prow[48] = (short)f2b_trunc(p3);
            }
        }

        bf16x8 vfr[4][2];
#pragma unroll
        for (int dt = 0; dt < 4; ++dt)
#pragma unroll
            for (int s = 0; s < 2; ++s)
                vfr[dt][s] = *(const bf16x8*)&Vc[(dt * 16 + l16) * 64 +
                                                 (((s << 2) + quad) ^ xk) * 8];

#pragma unroll
        for (int mt = 0; mt < 2; ++mt) {
            bf16x8 pf[2];
#pragma unroll
            for (int s = 0; s < 2; ++s) {
                union { struct { short4 lo, hi; } h2; bf16x8 v; } u;
                const short* base = &Pw[(mt * 16 + l16) * LDP + s * 32 + quad * 8];
                u.h2.lo = *(const short4*)(base);
                u.h2.hi = *(const short4*)(base + 4);
                pf[s] = u.v;
            }
#pragma unroll
            for (int dt = 0; dt < 4; ++dt)
#pragma unroll
                for (int s = 0; s < 2; ++s)
                    oacc[mt][dt] = __builtin_amdgcn_mfma_f32_16x16x32_bf16(
                        pf[s], vfr[dt][s], oacc[mt][dt], 0, 0, 0);
        }
        cur ^= 1;
    }

#pragma unroll
    for (int mt = 0; mt < 2; ++mt)
#pragma unroll
        for (int r = 0; r < 4; ++r) {
#pragma unroll
            for (int off = 1; off < 16; off <<= 1)
                l_r[mt][r] += __shfl_xor(l_r[mt][r], off);
            l_r[mt][r] = 1.f / l_r[mt][r];
        }

#pragma unroll
    for (int mt = 0; mt < 2; ++mt)
#pragma unroll
        for (int dt = 0; dt < 4; ++dt)
#pragma unroll
            for (int r = 0; r < 4; ++r) {
                const int row = q0 + w * 32 + mt * 16 + quad * 4 + r;
                ctx[(size_t)(b * 2048 + row) * 768 + h * 64 + dt * 16 + l16] =
                    f2b(oacc[mt][dt][r] * l_r[mt][r]);
            }
}

// ---------- LayerNorm over H=768, one block per row ----------
template <bool WB>
__global__ __launch_bounds__(256)
void layernorm_k(const float* __restrict__ y, const float* __restrict__ g,
                 const float* __restrict__ be, float* __restrict__ outf,
                 u16* __restrict__ outb) {
    const int row = blockIdx.x;
    const int tid = threadIdx.x;
    const float* yr = y + (size_t)row * 768;
    float v[3], s = 0.f, s2 = 0.f;
#pragma unroll
    for (int i = 0; i < 3; ++i) {
        float x = yr[tid + i * 256];
        v[i] = x; s += x; s2 += x * x;
    }
#pragma unroll
    for (int off = 32; off >= 1; off >>= 1) {
        s += __shfl_xor(s, off);
        s2 += __shfl_xor(s2, off);
    }
    __shared__ float red[2][4];
    const int w = tid >> 6;
    if ((tid & 63) == 0) { red[0][w] = s; red[1][w] = s2; }
    __syncthreads();
    s = red[0][0] + red[0][1] + red[0][2] + red[0][3];
    s2 = red[1][0] + red[1][1] + red[1][2] + red[1][3];
    const float mu = s * (1.f / 768.f);
    const float var = s2 * (1.f / 768.f) - mu * mu;
    const float rs = rsqrtf(var + 1e-12f);
#pragma unroll
    for (int i = 0; i < 3; ++i) {
        const int c = tid + i * 256;
        const float o = (v[i] - mu) * rs * g[c] + be[c];
        outf[(size_t)row * 768 + c] = o;
        if (WB) outb[(size_t)row * 768 + c] = f2b(o);
    }
}

// ---------- orchestration ----------
extern "C" void kernel_launch(void* const* d_in, const int* in_sizes, int n_in,
                              void* d_out, int out_size, void* d_ws, size_t ws_size,
                              hipStream_t stream) {
    const float* x    = (const float*)d_in[0];
    const float* wqkv = (const float*)d_in[1];
    const float* bqkv = (const float*)d_in[2];
    const float* wout = (const float*)d_in[3];
    const float* bout = (const float*)d_in[4];
    const float* wff1 = (const float*)d_in[5];
    const float* bff1 = (const float*)d_in[6];
    const float* wff2 = (const float*)d_in[7];
    const float* bff2 = (const float*)d_in[8];
    const float* g1   = (const float*)d_in[9];
    const float* be1  = (const float*)d_in[10];
    const float* g2   = (const float*)d_in[11];
    const float* be2  = (const float*)d_in[12];

    char* ws = (char*)d_ws;
    constexpr size_t o_xb    = 0;
    constexpr size_t o_wqkvT = o_xb    + (size_t)8192 * 768 * 2;
    constexpr size_t o_woutT = o_wqkvT + (size_t)2304 * 768 * 2;
    constexpr size_t o_wff1T = o_woutT + (size_t)768 * 768 * 2;
    constexpr size_t o_wff2T = o_wff1T + (size_t)3072 * 768 * 2;
    constexpr size_t o_qkv   = o_wff2T + (size_t)768 * 3072 * 2;
    constexpr size_t o_ctx   = o_qkv   + (size_t)8192 * 2304 * 2;
    constexpr size_t o_y     = o_ctx   + (size_t)8192 * 768 * 2;
    constexpr size_t o_x1f   = o_y     + (size_t)8192 * 768 * 4;
    constexpr size_t o_x1b   = o_x1f   + (size_t)8192 * 768 * 4;
    constexpr size_t o_h     = o_qkv;   // reuse qkv+ctx region
    constexpr size_t o_vt    = o_x1b;   // vt dead before x1b is written

    u16*   xb    = (u16*)(ws + o_xb);
    u16*   wqkvT = (u16*)(ws + o_wqkvT);
    u16*   woutT = (u16*)(ws + o_woutT);
    u16*   wff1T = (u16*)(ws + o_wff1T);
    u16*   wff2T = (u16*)(ws + o_wff2T);
    u16*   qkvb  = (u16*)(ws + o_qkv);
    u16*   ctxb  = (u16*)(ws + o_ctx);
    float* y     = (float*)(ws + o_y);
    float* x1f   = (float*)(ws + o_x1f);
    u16*   x1b   = (u16*)(ws + o_x1b);
    u16*   hb    = (u16*)(ws + o_h);
    u16*   vt    = (u16*)(ws + o_vt);

    // casts / weight transposes
    cast_bf16_x4<<<(8192 * 768 / 4 + 255) / 256, 256, 0, stream>>>(x, xb, 8192 * 768 / 4);
    transpose_cast<<<dim3(2304 / 32, 768 / 32),  dim3(32, 8), 0, stream>>>(wqkv, wqkvT, 768, 2304);
    transpose_cast<<<dim3(768 / 32,  768 / 32),  dim3(32, 8), 0, stream>>>(wout, woutT, 768, 768);
    transpose_cast<<<dim3(3072 / 32, 768 / 32),  dim3(32, 8), 0, stream>>>(wff1, wff1T, 768, 3072);
    transpose_cast<<<dim3(768 / 32,  3072 / 32), dim3(32, 8), 0, stream>>>(wff2, wff2T, 3072, 768);

    // qkv = x @ w_qkv + b ; q,k -> qkvb bf16, v -> vt transposed
    gemm_bf16<3><<<dim3(2304 / 128, 8192 / 128), 256, 0, stream>>>(
        xb, wqkvT, bqkv, qkvb, vt, 8192, 2304, 768);

    // fused attention -> ctx bf16 [8192, 768]
    attn_fused<<<dim3(2048 / 128, 12, 4), 256, 0, stream>>>(qkvb, vt, ctxb);

    // y = ctx @ w_out + b_out + x   -> f32  (64x128 tiles, 768 blocks)
    gemm_bf16_r64<<<dim3(768 / 128, 8192 / 64), 256, 0, stream>>>(
        ctxb, woutT, bout, x, y, 8192, 768, 768);

    // x1 = LN(y)  (f32 + bf16)
    layernorm_k<true><<<8192, 256, 0, stream>>>(y, g1, be1, x1f, x1b);

    // h = gelu(x1 @ w_ff1 + b_ff1)  -> bf16 [8192, 3072]
    gemm_bf16<2><<<dim3(3072 / 128, 8192 / 128), 256, 0, stream>>>(
        x1b, wff1T, bff1, hb, nullptr, 8192, 3072, 768);

    // y = h @ w_ff2 + b_ff2 + x1    -> f32 (reuses y; 64x128 tiles)
    gemm_bf16_r64<<<dim3(768 / 128, 8192 / 64), 256, 0, stream>>>(
        hb, wff2T, bff2, x1f, y, 8192, 768, 3072);

    // out = LN(y)
    layernorm_k<false><<<8192, 256, 0, stream>>>(y, g2, be2, (float*)d_out, nullptr);
}

// Round 7
// 403.172 us; speedup vs baseline: 1.0075x; 1.0075x over previous
//
#include <hip/hip_runtime.h>
#include <cstdint>
#include <cstddef>

typedef unsigned short u16;
typedef __attribute__((ext_vector_type(8))) short bf16x8;   // 8 bf16 = 4 VGPRs
typedef __attribute__((ext_vector_type(4))) float f32x4;    // MFMA 16x16 C/D

// ---------- helpers ----------
__device__ __forceinline__ u16 f2b(float f) {
    union { float f; unsigned u; } un; un.f = f;
    unsigned r = un.u + 0x7fffu + ((un.u >> 16) & 1u);   // RNE
    return (u16)(r >> 16);
}
__device__ __forceinline__ u16 f2b_trunc(float f) {
    union { float f; unsigned u; } un; un.f = f;
    return (u16)(un.u >> 16);
}
__device__ __forceinline__ float b2f(u16 h) {
    union { unsigned u; float f; } un; un.u = ((unsigned)h) << 16;
    return un.f;
}
__device__ __forceinline__ float fast_exp2(float x) {
#if __has_builtin(__builtin_amdgcn_exp2f)
    return __builtin_amdgcn_exp2f(x);
#else
    return exp2f(x);
#endif
}

// async global->LDS DMA, 16B per lane (wave-uniform base + lane*16 semantics).
__device__ __forceinline__ void stage16(const u16* g, u16* l) {
    __builtin_amdgcn_global_load_lds(
        (const __attribute__((address_space(1))) void*)g,
        (__attribute__((address_space(3))) void*)l, 16, 0, 0);
}

// ---------- cast fp32 -> bf16, 4 elems/thread ----------
__global__ __launch_bounds__(256) void cast_bf16_x4(const float* __restrict__ in,
                                                    u16* __restrict__ out, int n4) {
    int i = blockIdx.x * 256 + threadIdx.x;
    if (i >= n4) return;
    float4 v = ((const float4*)in)[i];
    ushort4 o;
    o.x = f2b(v.x); o.y = f2b(v.y); o.z = f2b(v.z); o.w = f2b(v.w);
    ((ushort4*)out)[i] = o;
}

// ---------- transpose + cast: w[K][N] f32 -> wT[N][K] bf16 ----------
__global__ __launch_bounds__(256) void transpose_cast(const float* __restrict__ in,
                                                      u16* __restrict__ out, int K, int N) {
    __shared__ float t[32][33];
    const int n0 = blockIdx.x * 32, k0 = blockIdx.y * 32;
    const int tx = threadIdx.x, ty = threadIdx.y;           // 32 x 8
#pragma unroll
    for (int i = 0; i < 4; ++i)
        t[ty + i * 8][tx] = in[(size_t)(k0 + ty + i * 8) * N + n0 + tx];
    __syncthreads();
#pragma unroll
    for (int i = 0; i < 4; ++i)
        out[(size_t)(n0 + ty + i * 8) * K + k0 + tx] = f2b(t[tx][ty + i * 8]);
}

// ---------- GEMM 128x128: C[M,N] = A[M,K] @ BT[N,K]^T  (+bias, epilogue) ----------
// EPI 0: bf16 out = acc + bias
// EPI 2: bf16 out = gelu_exact(acc + bias)
// EPI 3: qkv: cols<1536 -> bf16 out (q,k); cols>=1536 -> vt transposed
template <int EPI>
__global__ __launch_bounds__(256, 3)
void gemm_bf16(const u16* __restrict__ A, const u16* __restrict__ BT,
               const float* __restrict__ bias,
               void* __restrict__ outp, u16* __restrict__ vt, int M, int N, int K) {
    __shared__ __align__(16) u16 Ash[128 * 64];
    __shared__ __align__(16) u16 Bsh[128 * 64];
    const int m0 = blockIdx.y * 128, n0 = blockIdx.x * 128;
    const int tid = threadIdx.x;
    const int w = tid >> 6, lane = tid & 63;
    const int l16 = lane & 15, quad = lane >> 4;
    const int wm = (w >> 1) * 64, wn = (w & 1) * 64;

    const int srow = lane >> 3;                       // row within 8-row chunk
    const int sgrp = (lane & 7) ^ (srow & 7);         // logical 16B group to fetch
    const int xk = l16 & 7;                           // read-side swizzle key

    const f32x4 vzero = {0.f, 0.f, 0.f, 0.f};
    f32x4 acc[4][4];
#pragma unroll
    for (int i = 0; i < 4; ++i)
#pragma unroll
        for (int j = 0; j < 4; ++j) acc[i][j] = vzero;

    for (int k0 = 0; k0 < K; k0 += 64) {
#pragma unroll
        for (int it = 0; it < 4; ++it) {
            const int c = it * 4 + w;
            const int r = c * 8 + srow;
            stage16(A + (size_t)(m0 + r) * K + k0 + sgrp * 8, &Ash[c * 512 + lane * 8]);
        }
#pragma unroll
        for (int it = 0; it < 4; ++it) {
            const int c = it * 4 + w;
            const int r = c * 8 + srow;
            stage16(BT + (size_t)(n0 + r) * K + k0 + sgrp * 8, &Bsh[c * 512 + lane * 8]);
        }
        __syncthreads();

        bf16x8 af[4][2], bfr[4][2];
#pragma unroll
        for (int mt = 0; mt < 4; ++mt)
#pragma unroll
            for (int s = 0; s < 2; ++s)
                af[mt][s] = *(const bf16x8*)&Ash[(wm + mt * 16 + l16) * 64 +
                                                 (((s << 2) + quad) ^ xk) * 8];
#pragma unroll
        for (int nt = 0; nt < 4; ++nt)
#pragma unroll
            for (int s = 0; s < 2; ++s)
                bfr[nt][s] = *(const bf16x8*)&Bsh[(wn + nt * 16 + l16) * 64 +
                                                  (((s << 2) + quad) ^ xk) * 8];
#pragma unroll
        for (int mt = 0; mt < 4; ++mt)
#pragma unroll
            for (int nt = 0; nt < 4; ++nt)
#pragma unroll
                for (int s = 0; s < 2; ++s)
                    acc[mt][nt] = __builtin_amdgcn_mfma_f32_16x16x32_bf16(
                        af[mt][s], bfr[nt][s], acc[mt][nt], 0, 0, 0);
        __syncthreads();
    }

    if (EPI == 3 && n0 >= 1536) {
#pragma unroll
        for (int mt = 0; mt < 4; ++mt) {
#pragma unroll
            for (int nt = 0; nt < 4; ++nt) {
                const int col = n0 + wn + nt * 16 + l16;
                const int c = col - 1536;
                const int h = c >> 6, d = c & 63;
                const float bv = bias[col];
                const int row0 = m0 + wm + mt * 16 + quad * 4;
                const int b = row0 >> 11, tok = row0 & 2047;
                ushort4 o;
                o.x = f2b(acc[mt][nt][0] + bv);
                o.y = f2b(acc[mt][nt][1] + bv);
                o.z = f2b(acc[mt][nt][2] + bv);
                o.w = f2b(acc[mt][nt][3] + bv);
                *(ushort4*)&vt[(size_t)(((b * 12 + h) << 6) + d) * 2048 + tok] = o;
            }
        }
        return;
    }

#pragma unroll
    for (int mt = 0; mt < 4; ++mt) {
#pragma unroll
        for (int nt = 0; nt < 4; ++nt) {
            const int col = n0 + wn + nt * 16 + l16;
            const float bv = bias[col];
#pragma unroll
            for (int r = 0; r < 4; ++r) {
                const int row = m0 + wm + mt * 16 + quad * 4 + r;
                float v = acc[mt][nt][r] + bv;
                if (EPI == 2) {
                    v = 0.5f * v * (1.f + erff(v * 0.70710678118654752f));
                    ((u16*)outp)[(size_t)row * N + col] = f2b(v);
                } else {
                    ((u16*)outp)[(size_t)row * N + col] = f2b(v);
                }
            }
        }
    }
}

// ---------- GEMM 64x128, bf16 out = acc + bias + resid (resid f32 or bf16) ----------
template <bool RESF32>
__global__ __launch_bounds__(256, 4)
void gemm_bf16_r64(const u16* __restrict__ A, const u16* __restrict__ BT,
                   const float* __restrict__ bias, const void* __restrict__ resid,
                   u16* __restrict__ outp, int M, int N, int K) {
    __shared__ __align__(16) u16 Ash[64 * 64];
    __shared__ __align__(16) u16 Bsh[128 * 64];
    const int m0 = blockIdx.y * 64, n0 = blockIdx.x * 128;
    const int tid = threadIdx.x;
    const int w = tid >> 6, lane = tid & 63;
    const int l16 = lane & 15, quad = lane >> 4;
    const int wm = (w >> 1) * 32, wn = (w & 1) * 64;

    const int srow = lane >> 3;
    const int sgrp = (lane & 7) ^ (srow & 7);
    const int xk = l16 & 7;

    const f32x4 vzero = {0.f, 0.f, 0.f, 0.f};
    f32x4 acc[2][4];
#pragma unroll
    for (int i = 0; i < 2; ++i)
#pragma unroll
        for (int j = 0; j < 4; ++j) acc[i][j] = vzero;

    for (int k0 = 0; k0 < K; k0 += 64) {
#pragma unroll
        for (int it = 0; it < 2; ++it) {            // A: 8 chunks of 8 rows
            const int c = it * 4 + w;
            const int r = c * 8 + srow;
            stage16(A + (size_t)(m0 + r) * K + k0 + sgrp * 8, &Ash[c * 512 + lane * 8]);
        }
#pragma unroll
        for (int it = 0; it < 4; ++it) {            // B: 16 chunks
            const int c = it * 4 + w;
            const int r = c * 8 + srow;
            stage16(BT + (size_t)(n0 + r) * K + k0 + sgrp * 8, &Bsh[c * 512 + lane * 8]);
        }
        __syncthreads();

        bf16x8 af[2][2], bfr[4][2];
#pragma unroll
        for (int mt = 0; mt < 2; ++mt)
#pragma unroll
            for (int s = 0; s < 2; ++s)
                af[mt][s] = *(const bf16x8*)&Ash[(wm + mt * 16 + l16) * 64 +
                                                 (((s << 2) + quad) ^ xk) * 8];
#pragma unroll
        for (int nt = 0; nt < 4; ++nt)
#pragma unroll
            for (int s = 0; s < 2; ++s)
                bfr[nt][s] = *(const bf16x8*)&Bsh[(wn + nt * 16 + l16) * 64 +
                                                  (((s << 2) + quad) ^ xk) * 8];
#pragma unroll
        for (int mt = 0; mt < 2; ++mt)
#pragma unroll
            for (int nt = 0; nt < 4; ++nt)
#pragma unroll
                for (int s = 0; s < 2; ++s)
                    acc[mt][nt] = __builtin_amdgcn_mfma_f32_16x16x32_bf16(
                        af[mt][s], bfr[nt][s], acc[mt][nt], 0, 0, 0);
        __syncthreads();
    }

#pragma unroll
    for (int mt = 0; mt < 2; ++mt) {
#pragma unroll
        for (int nt = 0; nt < 4; ++nt) {
            const int col = n0 + wn + nt * 16 + l16;
            const float bv = bias[col];
#pragma unroll
            for (int r = 0; r < 4; ++r) {
                const int row = m0 + wm + mt * 16 + quad * 4 + r;
                const size_t idx = (size_t)row * N + col;
                const float rv = RESF32 ? ((const float*)resid)[idx]
                                        : b2f(((const u16*)resid)[idx]);
                outp[idx] = f2b(acc[mt][nt][r] + bv + rv);
            }
        }
    }
}

// ---------- fused flash attention, max-free softmax, split-K x2 ----------
// blockIdx.z: b = z>>1, half = z&1. Each half processes 1024 tokens, writes
// UNNORMALIZED O-partial (f32) and per-row l-partial; combine kernel merges.
__global__ __launch_bounds__(256, 4)
void attn_fused(const u16* __restrict__ qkv, const u16* __restrict__ vt,
                float* __restrict__ O0, float* __restrict__ O1,
                float* __restrict__ lbuf) {
    constexpr int LDP = 68;   // P per wave [q(32)][tok(64)]
    __shared__ __align__(16) u16 Ksh[64 * 64];
    __shared__ __align__(16) u16 Vsh[64 * 64];
    __shared__ __align__(16) short Psh[4 * 32 * LDP];

    const int q0 = blockIdx.x * 128;
    const int h = blockIdx.y;
    const int b = blockIdx.z >> 1, half = blockIdx.z & 1;
    const int tid = threadIdx.x;
    const int w = tid >> 6, lane = tid & 63, l16 = lane & 15, quad = lane >> 4;
    short* Pw = Psh + w * 32 * LDP;
    float* Op = half ? O1 : O0;

    const int srow = lane >> 3;
    const int sgrp = (lane & 7) ^ (srow & 7);
    const int xk = l16 & 7;

    const u16* Qp = qkv + (size_t)b * 2048 * 2304 + h * 64;
    const u16* Kp = Qp + 768;
    const u16* Vtp = vt + ((size_t)(b * 12 + h) << 6) * 2048;

    bf16x8 qf[2][2];
#pragma unroll
    for (int mt = 0; mt < 2; ++mt)
#pragma unroll
        for (int s = 0; s < 2; ++s)
            qf[mt][s] = *(const bf16x8*)(Qp +
                (size_t)(q0 + w * 32 + mt * 16 + l16) * 2304 + s * 32 + quad * 8);

    const f32x4 vzero = {0.f, 0.f, 0.f, 0.f};
    f32x4 oacc[2][4];
    float l_r[2][4];
#pragma unroll
    for (int mt = 0; mt < 2; ++mt) {
#pragma unroll
        for (int dt = 0; dt < 4; ++dt) oacc[mt][dt] = vzero;
#pragma unroll
        for (int r = 0; r < 4; ++r) l_r[mt][r] = 0.f;
    }

    constexpr float SCALE = 0.18033688011112042f;   // log2(e)/8
    const int kt0 = half * 1024;

    for (int kt = kt0; kt < kt0 + 1024; kt += 64) {
#pragma unroll
        for (int it = 0; it < 2; ++it) {
            const int c = it * 4 + w;
            const int r = c * 8 + srow;
            stage16(Kp + (size_t)(kt + r) * 2304 + sgrp * 8, &Ksh[c * 512 + lane * 8]);
        }
#pragma unroll
        for (int it = 0; it < 2; ++it) {
            const int c = it * 4 + w;
            const int r = c * 8 + srow;      // r = d
            stage16(Vtp + (size_t)r * 2048 + kt + sgrp * 8, &Vsh[c * 512 + lane * 8]);
        }
        __syncthreads();

        bf16x8 kfr[4][2];
#pragma unroll
        for (int nt = 0; nt < 4; ++nt)
#pragma unroll
            for (int s = 0; s < 2; ++s)
                kfr[nt][s] = *(const bf16x8*)&Ksh[(nt * 16 + l16) * 64 +
                                                  (((s << 2) + quad) ^ xk) * 8];

        f32x4 sacc[2][4];
#pragma unroll
        for (int mt = 0; mt < 2; ++mt)
#pragma unroll
            for (int nt = 0; nt < 4; ++nt) {
                sacc[mt][nt] = vzero;
#pragma unroll
                for (int s = 0; s < 2; ++s)
                    sacc[mt][nt] = __builtin_amdgcn_mfma_f32_16x16x32_bf16(
                        qf[mt][s], kfr[nt][s], sacc[mt][nt], 0, 0, 0);
            }

#pragma unroll
        for (int mt = 0; mt < 2; ++mt) {
#pragma unroll
            for (int r = 0; r < 4; ++r) {
                float p0 = fast_exp2(sacc[mt][0][r] * SCALE);
                float p1 = fast_exp2(sacc[mt][1][r] * SCALE);
                float p2 = fast_exp2(sacc[mt][2][r] * SCALE);
                float p3 = fast_exp2(sacc[mt][3][r] * SCALE);
                l_r[mt][r] += (p0 + p1) + (p2 + p3);
                short* prow = &Pw[(mt * 16 + quad * 4 + r) * LDP + l16];
                prow[0]  = (short)f2b_trunc(p0);
                prow[16] = (short)f2b_trunc(p1);
                prow[32] = (short)f2b_trunc(p2);
                prow[48] = (short)f2b_trunc(p3);
            }
        }

        bf16x8 vfr[4][2];
#pragma unroll
        for (int dt = 0; dt < 4; ++dt)
#pragma unroll
            for (int s = 0; s < 2; ++s)
                vfr[dt][s] = *(const bf16x8*)&Vsh[(dt * 16 + l16) * 64 +
                                                  (((s << 2) + quad) ^ xk) * 8];

#pragma unroll
        for (int mt = 0; mt < 2; ++mt) {
            bf16x8 pf[2];
#pragma unroll
            for (int s = 0; s < 2; ++s) {
                union { struct { short4 lo, hi; } h2; bf16x8 v; } u;
                const short* base = &Pw[(mt * 16 + l16) * LDP + s * 32 + quad * 8];
                u.h2.lo = *(const short4*)(base);
                u.h2.hi = *(const short4*)(base + 4);
                pf[s] = u.v;
            }
#pragma unroll
            for (int dt = 0; dt < 4; ++dt)
#pragma unroll
                for (int s = 0; s < 2; ++s)
                    oacc[mt][dt] = __builtin_amdgcn_mfma_f32_16x16x32_bf16(
                        pf[s], vfr[dt][s], oacc[mt][dt], 0, 0, 0);
        }
        __syncthreads();
    }

    // reduce l over the 16-lane col group; all lanes end with the row sum
#pragma unroll
    for (int mt = 0; mt < 2; ++mt)
#pragma unroll
        for (int r = 0; r < 4; ++r)
#pragma unroll
            for (int off = 1; off < 16; off <<= 1)
                l_r[mt][r] += __shfl_xor(l_r[mt][r], off);

    // lane l16==0 writes l partials: lbuf[((half*4+b)*12+h)*2048 + row]
    if (l16 == 0) {
        float* lb = lbuf + ((size_t)((half * 4 + b) * 12 + h)) * 2048;
#pragma unroll
        for (int mt = 0; mt < 2; ++mt)
#pragma unroll
            for (int r = 0; r < 4; ++r)
                lb[q0 + w * 32 + mt * 16 + quad * 4 + r] = l_r[mt][r];
    }

    // write unnormalized O partial (f32)
#pragma unroll
    for (int mt = 0; mt < 2; ++mt)
#pragma unroll
        for (int dt = 0; dt < 4; ++dt)
#pragma unroll
            for (int r = 0; r < 4; ++r) {
                const int row = q0 + w * 32 + mt * 16 + quad * 4 + r;
                Op[(size_t)(b * 2048 + row) * 768 + h * 64 + dt * 16 + l16] =
                    oacc[mt][dt][r];
            }
}

// ---------- combine split-K attention partials -> ctx bf16 ----------
__global__ __launch_bounds__(192)
void attn_combine(const float* __restrict__ O0, const float* __restrict__ O1,
                  const float* __restrict__ lbuf, u16* __restrict__ ctx) {
    const int r = blockIdx.x;            // token row 0..8191
    const int tid = threadIdx.x;         // 192 threads x float4 = 768
    const int b = r >> 11, q = r & 2047;
    const int h = tid >> 4;
    const float l0 = lbuf[((size_t)(b * 12 + h)) * 2048 + q];
    const float l1 = lbuf[((size_t)((4 + b) * 12 + h)) * 2048 + q];
    const float inv = 1.f / (l0 + l1);
    const float4 a = ((const float4*)O0)[(size_t)r * 192 + tid];
    const float4 c = ((const float4*)O1)[(size_t)r * 192 + tid];
    ushort4 o;
    o.x = f2b((a.x + c.x) * inv);
    o.y = f2b((a.y + c.y) * inv);
    o.z = f2b((a.z + c.z) * inv);
    o.w = f2b((a.w + c.w) * inv);
    ((ushort4*)ctx)[(size_t)r * 192 + tid] = o;
}

// ---------- LayerNorm over H=768 (bf16 in); OUTF32 ? f32 out : bf16 out ----------
template <bool OUTF32>
__global__ __launch_bounds__(256)
void layernorm_k(const u16* __restrict__ y, const float* __restrict__ g,
                 const float* __restrict__ be, float* __restrict__ outf,
                 u16* __restrict__ outb) {
    const int row = blockIdx.x;
    const int tid = threadIdx.x;
    const u16* yr = y + (size_t)row * 768;
    float v[3], s = 0.f, s2 = 0.f;
#pragma unroll
    for (int i = 0; i < 3; ++i) {
        float x = b2f(yr[tid + i * 256]);
        v[i] = x; s += x; s2 += x * x;
    }
#pragma unroll
    for (int off = 32; off >= 1; off >>= 1) {
        s += __shfl_xor(s, off);
        s2 += __shfl_xor(s2, off);
    }
    __shared__ float red[2][4];
    const int w = tid >> 6;
    if ((tid & 63) == 0) { red[0][w] = s; red[1][w] = s2; }
    __syncthreads();
    s = red[0][0] + red[0][1] + red[0][2] + red[0][3];
    s2 = red[1][0] + red[1][1] + red[1][2] + red[1][3];
    const float mu = s * (1.f / 768.f);
    const float var = s2 * (1.f / 768.f) - mu * mu;
    const float rs = rsqrtf(var + 1e-12f);
#pragma unroll
    for (int i = 0; i < 3; ++i) {
        const int c = tid + i * 256;
        const float o = (v[i] - mu) * rs * g[c] + be[c];
        if (OUTF32) outf[(size_t)row * 768 + c] = o;
        else        outb[(size_t)row * 768 + c] = f2b(o);
    }
}

// ---------- orchestration ----------
extern "C" void kernel_launch(void* const* d_in, const int* in_sizes, int n_in,
                              void* d_out, int out_size, void* d_ws, size_t ws_size,
                              hipStream_t stream) {
    const float* x    = (const float*)d_in[0];
    const float* wqkv = (const float*)d_in[1];
    const float* bqkv = (const float*)d_in[2];
    const float* wout = (const float*)d_in[3];
    const float* bout = (const float*)d_in[4];
    const float* wff1 = (const float*)d_in[5];
    const float* bff1 = (const float*)d_in[6];
    const float* wff2 = (const float*)d_in[7];
    const float* bff2 = (const float*)d_in[8];
    const float* g1   = (const float*)d_in[9];
    const float* be1  = (const float*)d_in[10];
    const float* g2   = (const float*)d_in[11];
    const float* be2  = (const float*)d_in[12];

    char* ws = (char*)d_ws;
    constexpr size_t o_xb    = 0;                                    // 12.58M
    constexpr size_t o_wqkvT = o_xb    + (size_t)8192 * 768 * 2;     // 3.54M (lbuf after qkv gemm)
    constexpr size_t o_woutT = o_wqkvT + (size_t)2304 * 768 * 2;
    constexpr size_t o_wff1T = o_woutT + (size_t)768 * 768 * 2;
    constexpr size_t o_wff2T = o_wff1T + (size_t)3072 * 768 * 2;
    constexpr size_t o_qkv   = o_wff2T + (size_t)768 * 3072 * 2;     // 37.75M
    constexpr size_t o_ctx   = o_qkv   + (size_t)8192 * 2304 * 2;    // 12.58M
    constexpr size_t o_y     = o_ctx   + (size_t)8192 * 768 * 2;     // 25.17M: O0, later yb/y2b
    constexpr size_t o_x1f   = o_y     + (size_t)8192 * 768 * 4;     // 25.17M: O1
    constexpr size_t o_x1b   = o_x1f   + (size_t)8192 * 768 * 4;     // 12.58M: vt, later x1b
    constexpr size_t o_h     = o_qkv;   // hb reuses qkv+ctx region (50.33M)
    constexpr size_t o_vt    = o_x1b;
    constexpr size_t o_l     = o_wqkvT; // lbuf (786KB) reuses wqkvT after qkv gemm

    u16*   xb    = (u16*)(ws + o_xb);
    u16*   wqkvT = (u16*)(ws + o_wqkvT);
    u16*   woutT = (u16*)(ws + o_woutT);
    u16*   wff1T = (u16*)(ws + o_wff1T);
    u16*   wff2T = (u16*)(ws + o_wff2T);
    u16*   qkvb  = (u16*)(ws + o_qkv);
    u16*   ctxb  = (u16*)(ws + o_ctx);
    float* O0    = (float*)(ws + o_y);
    float* O1    = (float*)(ws + o_x1f);
    u16*   yb    = (u16*)(ws + o_y);    // after combine, y bf16
    u16*   x1b   = (u16*)(ws + o_x1b);
    u16*   hb    = (u16*)(ws + o_h);
    u16*   vt    = (u16*)(ws + o_vt);
    float* lbuf  = (float*)(ws + o_l);

    // casts / weight transposes
    cast_bf16_x4<<<(8192 * 768 / 4 + 255) / 256, 256, 0, stream>>>(x, xb, 8192 * 768 / 4);
    transpose_cast<<<dim3(2304 / 32, 768 / 32),  dim3(32, 8), 0, stream>>>(wqkv, wqkvT, 768, 2304);
    transpose_cast<<<dim3(768 / 32,  768 / 32),  dim3(32, 8), 0, stream>>>(wout, woutT, 768, 768);
    transpose_cast<<<dim3(3072 / 32, 768 / 32),  dim3(32, 8), 0, stream>>>(wff1, wff1T, 768, 3072);
    transpose_cast<<<dim3(768 / 32,  3072 / 32), dim3(32, 8), 0, stream>>>(wff2, wff2T, 3072, 768);

    // qkv = x @ w_qkv + b ; q,k -> qkvb bf16, v -> vt transposed
    gemm_bf16<3><<<dim3(2304 / 128, 8192 / 128), 256, 0, stream>>>(
        xb, wqkvT, bqkv, qkvb, vt, 8192, 2304, 768);

    // split-K attention partials (overwrites wqkvT region with lbuf)
    attn_fused<<<dim3(2048 / 128, 12, 8), 256, 0, stream>>>(qkvb, vt, O0, O1, lbuf);
    attn_combine<<<8192, 192, 0, stream>>>(O0, O1, lbuf, ctxb);

    // y = ctx @ w_out + b_out + x  -> bf16 (O0 region dead after combine)
    gemm_bf16_r64<true><<<dim3(768 / 128, 8192 / 64), 256, 0, stream>>>(
        ctxb, woutT, bout, x, yb, 8192, 768, 768);

    // x1 = LN(y) -> bf16 (vt dead after attention)
    layernorm_k<false><<<8192, 256, 0, stream>>>(yb, g1, be1, nullptr, x1b);

    // h = gelu(x1 @ w_ff1 + b_ff1) -> bf16 [8192, 3072]
    gemm_bf16<2><<<dim3(3072 / 128, 8192 / 128), 256, 0, stream>>>(
        x1b, wff1T, bff1, hb, nullptr, 8192, 3072, 768);

    // y2 = h @ w_ff2 + b_ff2 + x1 -> bf16 (yb dead after LN1)
    gemm_bf16_r64<false><<<dim3(768 / 128, 8192 / 64), 256, 0, stream>>>(
        hb, wff2T, bff2, x1b, yb, 8192, 768, 3072);

    // out = LN(y2) -> f32
    layernorm_k<true><<<8192, 256, 0, stream>>>(yb, g2, be2, (float*)d_out, nullptr);
}

// Round 8
// 380.710 us; speedup vs baseline: 1.0669x; 1.0590x over previous
//
#include <hip/hip_runtime.h>
#include <cstdint>
#include <cstddef>

typedef unsigned short u16;
typedef __attribute__((ext_vector_type(8))) short bf16x8;    // 8 bf16 = 4 VGPRs
typedef __attribute__((ext_vector_type(4))) float f32x4;     // 16x16 C/D
typedef __attribute__((ext_vector_type(16))) float f32x16;   // 32x32 C/D

// ---------- helpers ----------
__device__ __forceinline__ u16 f2b(float f) {
    union { float f; unsigned u; } un; un.f = f;
    unsigned r = un.u + 0x7fffu + ((un.u >> 16) & 1u);   // RNE
    return (u16)(r >> 16);
}
__device__ __forceinline__ u16 f2b_trunc(float f) {
    union { float f; unsigned u; } un; un.f = f;
    return (u16)(un.u >> 16);
}
__device__ __forceinline__ float b2f(u16 h) {
    union { unsigned u; float f; } un; un.u = ((unsigned)h) << 16;
    return un.f;
}
__device__ __forceinline__ float fast_exp2(float x) {
#if __has_builtin(__builtin_amdgcn_exp2f)
    return __builtin_amdgcn_exp2f(x);
#else
    return exp2f(x);
#endif
}

// async global->LDS DMA, 16B per lane (wave-uniform base + lane*16 semantics).
__device__ __forceinline__ void stage16(const u16* g, u16* l) {
    __builtin_amdgcn_global_load_lds(
        (const __attribute__((address_space(1))) void*)g,
        (__attribute__((address_space(3))) void*)l, 16, 0, 0);
}

// ---------- fused prologue: x cast + 4 weight transposes ----------
// grid: [0,6144) x-cast; then wqkvT(1728), woutT(576), wff1T(2304), wff2T(2304)
__global__ __launch_bounds__(256)
void prep(const float* __restrict__ x, u16* __restrict__ xb,
          const float* __restrict__ wqkv, u16* __restrict__ wqkvT,
          const float* __restrict__ wout, u16* __restrict__ woutT,
          const float* __restrict__ wff1, u16* __restrict__ wff1T,
          const float* __restrict__ wff2, u16* __restrict__ wff2T) {
    __shared__ float t[32][33];
    const int tid = threadIdx.x;
    int bid = blockIdx.x;
    if (bid < 6144) {
        const int i = bid * 256 + tid;
        float4 v = ((const float4*)x)[i];
        ushort4 o;
        o.x = f2b(v.x); o.y = f2b(v.y); o.z = f2b(v.z); o.w = f2b(v.w);
        ((ushort4*)xb)[i] = o;
        return;
    }
    int tt = bid - 6144;
    const float* in; u16* out; int K, N, bx, by;
    if (tt < 1728)      { in = wqkv; out = wqkvT; K = 768;  N = 2304; bx = tt % 72; by = tt / 72; }
    else if ((tt -= 1728) < 576)  { in = wout; out = woutT; K = 768;  N = 768;  bx = tt % 24; by = tt / 24; }
    else if ((tt -= 576) < 2304)  { in = wff1; out = wff1T; K = 768;  N = 3072; bx = tt % 96; by = tt / 96; }
    else { tt -= 2304;    in = wff2; out = wff2T; K = 3072; N = 768;  bx = tt % 24; by = tt / 24; }
    const int n0 = bx * 32, k0 = by * 32;
    const int tx = tid & 31, ty = tid >> 5;     // 32 x 8
#pragma unroll
    for (int i = 0; i < 4; ++i)
        t[ty + i * 8][tx] = in[(size_t)(k0 + ty + i * 8) * N + n0 + tx];
    __syncthreads();
#pragma unroll
    for (int i = 0; i < 4; ++i)
        out[(size_t)(n0 + ty + i * 8) * K + k0 + tx] = f2b(t[tx][ty + i * 8]);
}

// ---------- GEMM 128x128, 32x32x16 MFMA ----------
// LDS: unpadded [row][64] XOR-swizzled 16B groups, staged via global_load_lds.
// EPI 0: bf16 out = acc + bias
// EPI 2: bf16 out = gelu_exact(acc + bias)
// EPI 3: qkv: cols<1536 -> bf16 out (q,k); cols>=1536 -> vt transposed
template <int EPI>
__global__ __launch_bounds__(256, 3)
void gemm_bf16(const u16* __restrict__ A, const u16* __restrict__ BT,
               const float* __restrict__ bias,
               void* __restrict__ outp, u16* __restrict__ vt, int M, int N, int K) {
    __shared__ __align__(16) u16 Ash[128 * 64];
    __shared__ __align__(16) u16 Bsh[128 * 64];
    const int m0 = blockIdx.y * 128, n0 = blockIdx.x * 128;
    const int tid = threadIdx.x;
    const int w = tid >> 6, lane = tid & 63;
    const int l32 = lane & 31, half = lane >> 5;
    const int wm = (w >> 1) * 64, wn = (w & 1) * 64;

    const int srow = lane >> 3;
    const int sgrp = (lane & 7) ^ (srow & 7);
    const int xr = l32 & 7;                       // read-side swizzle key (= row&7)

    f32x16 acc[2][2];
#pragma unroll
    for (int i = 0; i < 2; ++i)
#pragma unroll
        for (int j = 0; j < 2; ++j)
#pragma unroll
            for (int e = 0; e < 16; ++e) acc[i][j][e] = 0.f;

    for (int k0 = 0; k0 < K; k0 += 64) {
#pragma unroll
        for (int it = 0; it < 4; ++it) {
            const int c = it * 4 + w;
            const int r = c * 8 + srow;
            stage16(A + (size_t)(m0 + r) * K + k0 + sgrp * 8, &Ash[c * 512 + lane * 8]);
        }
#pragma unroll
        for (int it = 0; it < 4; ++it) {
            const int c = it * 4 + w;
            const int r = c * 8 + srow;
            stage16(BT + (size_t)(n0 + r) * K + k0 + sgrp * 8, &Bsh[c * 512 + lane * 8]);
        }
        __syncthreads();

        bf16x8 af[2][4], bfr[2][4];
#pragma unroll
        for (int mt = 0; mt < 2; ++mt)
#pragma unroll
            for (int kc = 0; kc < 4; ++kc)
                af[mt][kc] = *(const bf16x8*)&Ash[(wm + mt * 32 + l32) * 64 +
                                                  (((kc << 1) + half) ^ xr) * 8];
#pragma unroll
        for (int nt = 0; nt < 2; ++nt)
#pragma unroll
            for (int kc = 0; kc < 4; ++kc)
                bfr[nt][kc] = *(const bf16x8*)&Bsh[(wn + nt * 32 + l32) * 64 +
                                                   (((kc << 1) + half) ^ xr) * 8];
#pragma unroll
        for (int mt = 0; mt < 2; ++mt)
#pragma unroll
            for (int nt = 0; nt < 2; ++nt)
#pragma unroll
                for (int kc = 0; kc < 4; ++kc)
                    acc[mt][nt] = __builtin_amdgcn_mfma_f32_32x32x16_bf16(
                        af[mt][kc], bfr[nt][kc], acc[mt][nt], 0, 0, 0);
        __syncthreads();
    }

    if (EPI == 3 && n0 >= 1536) {
        // V columns -> vt[((b*12+h)*64+d)*2048 + tok], 4 consecutive toks/store
#pragma unroll
        for (int mt = 0; mt < 2; ++mt) {
#pragma unroll
            for (int nt = 0; nt < 2; ++nt) {
                const int col = n0 + wn + nt * 32 + l32;
                const int c = col - 1536;
                const int h = c >> 6, d = c & 63;
                const float bv = bias[col];
#pragma unroll
                for (int rq = 0; rq < 4; ++rq) {
                    const int row0 = m0 + wm + mt * 32 + rq * 8 + half * 4;
                    const int b = row0 >> 11, tok = row0 & 2047;
                    ushort4 o;
                    o.x = f2b(acc[mt][nt][rq * 4 + 0] + bv);
                    o.y = f2b(acc[mt][nt][rq * 4 + 1] + bv);
                    o.z = f2b(acc[mt][nt][rq * 4 + 2] + bv);
                    o.w = f2b(acc[mt][nt][rq * 4 + 3] + bv);
                    *(ushort4*)&vt[(size_t)(((b * 12 + h) << 6) + d) * 2048 + tok] = o;
                }
            }
        }
        return;
    }

#pragma unroll
    for (int mt = 0; mt < 2; ++mt) {
#pragma unroll
        for (int nt = 0; nt < 2; ++nt) {
            const int col = n0 + wn + nt * 32 + l32;
            const float bv = bias[col];
#pragma unroll
            for (int reg = 0; reg < 16; ++reg) {
                const int row = m0 + wm + mt * 32 + (reg & 3) + 8 * (reg >> 2) + 4 * half;
                float v = acc[mt][nt][reg] + bv;
                if (EPI == 2)
                    v = 0.5f * v * (1.f + erff(v * 0.70710678118654752f));
                ((u16*)outp)[(size_t)row * N + col] = f2b(v);
            }
        }
    }
}

// ---------- GEMM 64x128 (32x32x16), bf16 out = acc + bias + resid ----------
template <bool RESF32>
__global__ __launch_bounds__(256, 4)
void gemm_bf16_r64(const u16* __restrict__ A, const u16* __restrict__ BT,
                   const float* __restrict__ bias, const void* __restrict__ resid,
                   u16* __restrict__ outp, int M, int N, int K) {
    __shared__ __align__(16) u16 Ash[64 * 64];
    __shared__ __align__(16) u16 Bsh[128 * 64];
    const int m0 = blockIdx.y * 64, n0 = blockIdx.x * 128;
    const int tid = threadIdx.x;
    const int w = tid >> 6, lane = tid & 63;
    const int l32 = lane & 31, half = lane >> 5;
    const int wm = (w >> 1) * 32, wn = (w & 1) * 64;

    const int srow = lane >> 3;
    const int sgrp = (lane & 7) ^ (srow & 7);
    const int xr = l32 & 7;

    f32x16 acc[2];
#pragma unroll
    for (int j = 0; j < 2; ++j)
#pragma unroll
        for (int e = 0; e < 16; ++e) acc[j][e] = 0.f;

    for (int k0 = 0; k0 < K; k0 += 64) {
#pragma unroll
        for (int it = 0; it < 2; ++it) {
            const int c = it * 4 + w;
            const int r = c * 8 + srow;
            stage16(A + (size_t)(m0 + r) * K + k0 + sgrp * 8, &Ash[c * 512 + lane * 8]);
        }
#pragma unroll
        for (int it = 0; it < 4; ++it) {
            const int c = it * 4 + w;
            const int r = c * 8 + srow;
            stage16(BT + (size_t)(n0 + r) * K + k0 + sgrp * 8, &Bsh[c * 512 + lane * 8]);
        }
        __syncthreads();

        bf16x8 af[4], bfr[2][4];
#pragma unroll
        for (int kc = 0; kc < 4; ++kc)
            af[kc] = *(const bf16x8*)&Ash[(wm + l32) * 64 + (((kc << 1) + half) ^ xr) * 8];
#pragma unroll
        for (int nt = 0; nt < 2; ++nt)
#pragma unroll
            for (int kc = 0; kc < 4; ++kc)
                bfr[nt][kc] = *(const bf16x8*)&Bsh[(wn + nt * 32 + l32) * 64 +
                                                   (((kc << 1) + half) ^ xr) * 8];
#pragma unroll
        for (int nt = 0; nt < 2; ++nt)
#pragma unroll
            for (int kc = 0; kc < 4; ++kc)
                acc[nt] = __builtin_amdgcn_mfma_f32_32x32x16_bf16(
                    af[kc], bfr[nt][kc], acc[nt], 0, 0, 0);
        __syncthreads();
    }

#pragma unroll
    for (int nt = 0; nt < 2; ++nt) {
        const int col = n0 + wn + nt * 32 + l32;
        const float bv = bias[col];
#pragma unroll
        for (int reg = 0; reg < 16; ++reg) {
            const int row = m0 + wm + (reg & 3) + 8 * (reg >> 2) + 4 * half;
            const size_t idx = (size_t)row * N + col;
            const float rv = RESF32 ? ((const float*)resid)[idx]
                                    : b2f(((const u16*)resid)[idx]);
            outp[idx] = f2b(acc[nt][reg] + bv + rv);
        }
    }
}

// ---------- fused flash attention, max-free softmax (round-4 form) ----------
__global__ __launch_bounds__(256, 2)
void attn_fused(const u16* __restrict__ qkv, const u16* __restrict__ vt,
                u16* __restrict__ ctx) {
    constexpr int LDP = 68;   // P per wave [q(32)][tok(64)]
    __shared__ __align__(16) u16 Ksh[64 * 64];
    __shared__ __align__(16) u16 Vsh[64 * 64];
    __shared__ __align__(16) short Psh[4 * 32 * LDP];

    const int q0 = blockIdx.x * 128;
    const int h = blockIdx.y, b = blockIdx.z;
    const int tid = threadIdx.x;
    const int w = tid >> 6, lane = tid & 63, l16 = lane & 15, quad = lane >> 4;
    short* Pw = Psh + w * 32 * LDP;

    const int srow = lane >> 3;
    const int sgrp = (lane & 7) ^ (srow & 7);
    const int xk = l16 & 7;

    const u16* Qp = qkv + (size_t)b * 2048 * 2304 + h * 64;
    const u16* Kp = Qp + 768;
    const u16* Vtp = vt + ((size_t)(b * 12 + h) << 6) * 2048;

    bf16x8 qf[2][2];
#pragma unroll
    for (int mt = 0; mt < 2; ++mt)
#pragma unroll
        for (int s = 0; s < 2; ++s)
            qf[mt][s] = *(const bf16x8*)(Qp +
                (size_t)(q0 + w * 32 + mt * 16 + l16) * 2304 + s * 32 + quad * 8);

    const f32x4 vzero = {0.f, 0.f, 0.f, 0.f};
    f32x4 oacc[2][4];
    float l_r[2][4];
#pragma unroll
    for (int mt = 0; mt < 2; ++mt) {
#pragma unroll
        for (int dt = 0; dt < 4; ++dt) oacc[mt][dt] = vzero;
#pragma unroll
        for (int r = 0; r < 4; ++r) l_r[mt][r] = 0.f;
    }

    constexpr float SCALE = 0.18033688011112042f;   // log2(e)/8

    for (int kt = 0; kt < 2048; kt += 64) {
#pragma unroll
        for (int it = 0; it < 2; ++it) {
            const int c = it * 4 + w;
            const int r = c * 8 + srow;
            stage16(Kp + (size_t)(kt + r) * 2304 + sgrp * 8, &Ksh[c * 512 + lane * 8]);
        }
#pragma unroll
        for (int it = 0; it < 2; ++it) {
            const int c = it * 4 + w;
            const int r = c * 8 + srow;      // r = d
            stage16(Vtp + (size_t)r * 2048 + kt + sgrp * 8, &Vsh[c * 512 + lane * 8]);
        }
        __syncthreads();

        bf16x8 kfr[4][2];
#pragma unroll
        for (int nt = 0; nt < 4; ++nt)
#pragma unroll
            for (int s = 0; s < 2; ++s)
                kfr[nt][s] = *(const bf16x8*)&Ksh[(nt * 16 + l16) * 64 +
                                                  (((s << 2) + quad) ^ xk) * 8];

        f32x4 sacc[2][4];
#pragma unroll
        for (int mt = 0; mt < 2; ++mt)
#pragma unroll
            for (int nt = 0; nt < 4; ++nt) {
                sacc[mt][nt] = vzero;
#pragma unroll
                for (int s = 0; s < 2; ++s)
                    sacc[mt][nt] = __builtin_amdgcn_mfma_f32_16x16x32_bf16(
                        qf[mt][s], kfr[nt][s], sacc[mt][nt], 0, 0, 0);
            }

#pragma unroll
        for (int mt = 0; mt < 2; ++mt) {
#pragma unroll
            for (int r = 0; r < 4; ++r) {
                float p0 = fast_exp2(sacc[mt][0][r] * SCALE);
                float p1 = fast_exp2(sacc[mt][1][r] * SCALE);
                float p2 = fast_exp2(sacc[mt][2][r] * SCALE);
                float p3 = fast_exp2(sacc[mt][3][r] * SCALE);
                l_r[mt][r] += (p0 + p1) + (p2 + p3);
                short* prow = &Pw[(mt * 16 + quad * 4 + r) * LDP + l16];
                prow[0]  = (short)f2b_trunc(p0);
                prow[16] = (short)f2b_trunc(p1);
                prow[32] = (short)f2b_trunc(p2);
                prow[48] = (short)f2b_trunc(p3);
            }
        }

        bf16x8 vfr[4][2];
#pragma unroll
        for (int dt = 0; dt < 4; ++dt)
#pragma unroll
            for (int s = 0; s < 2; ++s)
                vfr[dt][s] = *(const bf16x8*)&Vsh[(dt * 16 + l16) * 64 +
                                                  (((s << 2) + quad) ^ xk) * 8];

#pragma unroll
        for (int mt = 0; mt < 2; ++mt) {
            bf16x8 pf[2];
#pragma unroll
            for (int s = 0; s < 2; ++s) {
                union { struct { short4 lo, hi; } h2; bf16x8 v; } u;
                const short* base = &Pw[(mt * 16 + l16) * LDP + s * 32 + quad * 8];
                u.h2.lo = *(const short4*)(base);
                u.h2.hi = *(const short4*)(base + 4);
                pf[s] = u.v;
            }
#pragma unroll
            for (int dt = 0; dt < 4; ++dt)
#pragma unroll
                for (int s = 0; s < 2; ++s)
                    oacc[mt][dt] = __builtin_amdgcn_mfma_f32_16x16x32_bf16(
                        pf[s], vfr[dt][s], oacc[mt][dt], 0, 0, 0);
        }
        __syncthreads();
    }

#pragma unroll
    for (int mt = 0; mt < 2; ++mt)
#pragma unroll
        for (int r = 0; r < 4; ++r) {
#pragma unroll
            for (int off = 1; off < 16; off <<= 1)
                l_r[mt][r] += __shfl_xor(l_r[mt][r], off);
            l_r[mt][r] = 1.f / l_r[mt][r];
        }

#pragma unroll
    for (int mt = 0; mt < 2; ++mt)
#pragma unroll
        for (int dt = 0; dt < 4; ++dt)
#pragma unroll
            for (int r = 0; r < 4; ++r) {
                const int row = q0 + w * 32 + mt * 16 + quad * 4 + r;
                ctx[(size_t)(b * 2048 + row) * 768 + h * 64 + dt * 16 + l16] =
                    f2b(oacc[mt][dt][r] * l_r[mt][r]);
            }
}

// ---------- LayerNorm over H=768 (bf16 in); OUTF32 ? f32 out : bf16 out ----------
template <bool OUTF32>
__global__ __launch_bounds__(256)
void layernorm_k(const u16* __restrict__ y, const float* __restrict__ g,
                 const float* __restrict__ be, float* __restrict__ outf,
                 u16* __restrict__ outb) {
    const int row = blockIdx.x;
    const int tid = threadIdx.x;
    const u16* yr = y + (size_t)row * 768;
    float v[3], s = 0.f, s2 = 0.f;
#pragma unroll
    for (int i = 0; i < 3; ++i) {
        float x = b2f(yr[tid + i * 256]);
        v[i] = x; s += x; s2 += x * x;
    }
#pragma unroll
    for (int off = 32; off >= 1; off >>= 1) {
        s += __shfl_xor(s, off);
        s2 += __shfl_xor(s2, off);
    }
    __shared__ float red[2][4];
    const int w = tid >> 6;
    if ((tid & 63) == 0) { red[0][w] = s; red[1][w] = s2; }
    __syncthreads();
    s = red[0][0] + red[0][1] + red[0][2] + red[0][3];
    s2 = red[1][0] + red[1][1] + red[1][2] + red[1][3];
    const float mu = s * (1.f / 768.f);
    const float var = s2 * (1.f / 768.f) - mu * mu;
    const float rs = rsqrtf(var + 1e-12f);
#pragma unroll
    for (int i = 0; i < 3; ++i) {
        const int c = tid + i * 256;
        const float o = (v[i] - mu) * rs * g[c] + be[c];
        if (OUTF32) outf[(size_t)row * 768 + c] = o;
        else        outb[(size_t)row * 768 + c] = f2b(o);
    }
}

// ---------- orchestration ----------
extern "C" void kernel_launch(void* const* d_in, const int* in_sizes, int n_in,
                              void* d_out, int out_size, void* d_ws, size_t ws_size,
                              hipStream_t stream) {
    const float* x    = (const float*)d_in[0];
    const float* wqkv = (const float*)d_in[1];
    const float* bqkv = (const float*)d_in[2];
    const float* wout = (const float*)d_in[3];
    const float* bout = (const float*)d_in[4];
    const float* wff1 = (const float*)d_in[5];
    const float* bff1 = (const float*)d_in[6];
    const float* wff2 = (const float*)d_in[7];
    const float* bff2 = (const float*)d_in[8];
    const float* g1   = (const float*)d_in[9];
    const float* be1  = (const float*)d_in[10];
    const float* g2   = (const float*)d_in[11];
    const float* be2  = (const float*)d_in[12];

    char* ws = (char*)d_ws;
    constexpr size_t o_xb    = 0;
    constexpr size_t o_wqkvT = o_xb    + (size_t)8192 * 768 * 2;
    constexpr size_t o_woutT = o_wqkvT + (size_t)2304 * 768 * 2;
    constexpr size_t o_wff1T = o_woutT + (size_t)768 * 768 * 2;
    constexpr size_t o_wff2T = o_wff1T + (size_t)3072 * 768 * 2;
    constexpr size_t o_qkv   = o_wff2T + (size_t)768 * 3072 * 2;
    constexpr size_t o_ctx   = o_qkv   + (size_t)8192 * 2304 * 2;
    constexpr size_t o_y     = o_ctx   + (size_t)8192 * 768 * 2;
    constexpr size_t o_x1b   = o_y     + (size_t)8192 * 768 * 2;
    constexpr size_t o_vt    = o_x1b;   // vt dead before x1b is written
    constexpr size_t o_h     = o_qkv;   // hb reuses qkv+ctx region

    u16*   xb    = (u16*)(ws + o_xb);
    u16*   wqkvT = (u16*)(ws + o_wqkvT);
    u16*   woutT = (u16*)(ws + o_woutT);
    u16*   wff1T = (u16*)(ws + o_wff1T);
    u16*   wff2T = (u16*)(ws + o_wff2T);
    u16*   qkvb  = (u16*)(ws + o_qkv);
    u16*   ctxb  = (u16*)(ws + o_ctx);
    u16*   yb    = (u16*)(ws + o_y);
    u16*   x1b   = (u16*)(ws + o_x1b);
    u16*   hb    = (u16*)(ws + o_h);
    u16*   vt    = (u16*)(ws + o_vt);

    // fused prologue: x cast + 4 weight transposes
    prep<<<13056, 256, 0, stream>>>(x, xb, wqkv, wqkvT, wout, woutT,
                                    wff1, wff1T, wff2, wff2T);

    // qkv = x @ w_qkv + b ; q,k -> qkvb bf16, v -> vt transposed
    gemm_bf16<3><<<dim3(2304 / 128, 8192 / 128), 256, 0, stream>>>(
        xb, wqkvT, bqkv, qkvb, vt, 8192, 2304, 768);

    // fused attention -> ctx bf16 [8192, 768]
    attn_fused<<<dim3(2048 / 128, 12, 4), 256, 0, stream>>>(qkvb, vt, ctxb);

    // y = ctx @ w_out + b_out + x  -> bf16
    gemm_bf16_r64<true><<<dim3(768 / 128, 8192 / 64), 256, 0, stream>>>(
        ctxb, woutT, bout, x, yb, 8192, 768, 768);

    // x1 = LN(y) -> bf16 (vt dead after attention)
    layernorm_k<false><<<8192, 256, 0, stream>>>(yb, g1, be1, nullptr, x1b);

    // h = gelu(x1 @ w_ff1 + b_ff1) -> bf16 [8192, 3072]
    gemm_bf16<2><<<dim3(3072 / 128, 8192 / 128), 256, 0, stream>>>(
        x1b, wff1T, bff1, hb, nullptr, 8192, 3072, 768);

    // y2 = h @ w_ff2 + b_ff2 + x1 -> bf16 (yb dead after LN1)
    gemm_bf16_r64<false><<<dim3(768 / 128, 8192 / 64), 256, 0, stream>>>(
        hb, wff2T, bff2, x1b, yb, 8192, 768, 3072);

    // out = LN(y2) -> f32
    layernorm_k<true><<<8192, 256, 0, stream>>>(yb, g2, be2, (float*)d_out, nullptr);
}